// Round 12
// baseline (188.006 us; speedup 1.0000x reference)
//
#include <hip/hip_runtime.h>
#include <math.h>

#define Bv 4
#define Nv 3136
#define Cv 64
#define Hh 56
#define Ww 56
#define HIDv 256
#define TOPKv 8
#define TSP 520   // msfn ts row pitch (bf16): dword pitch % 32 == 4 -> conflict-free b128
#define LCP 584   // im2col row pitch (576+8): same property
#define XNP 72    // ln/proj LDS bf16 row pitch (64+8): dword pitch 36 % 32 == 4
#define KSPL 8    // key splits in k_attn_topk
#define KPS 392   // keys per split (3136/8)

constexpr float SCALE = 0.125f;   // d^-0.5, d=64
constexpr float EPS = 1e-5f;
constexpr float SBIAS = 128.0f;   // score bias: all packed scores positive

typedef short bf16x8 __attribute__((ext_vector_type(8)));
typedef float f32x4 __attribute__((ext_vector_type(4)));

#define CSWAP(a, b) { unsigned int _hi = max(a, b); unsigned int _lo = min(a, b); a = _hi; b = _lo; }
// descending bitonic clean of 8 (input: bitonic), 3 stages
#define BITONIC8(T) \
  CSWAP(T[0], T[4]); CSWAP(T[1], T[5]); CSWAP(T[2], T[6]); CSWAP(T[3], T[7]); \
  CSWAP(T[0], T[2]); CSWAP(T[1], T[3]); CSWAP(T[4], T[6]); CSWAP(T[5], T[7]); \
  CSWAP(T[0], T[1]); CSWAP(T[2], T[3]); CSWAP(T[4], T[5]); CSWAP(T[6], T[7]);

__device__ __forceinline__ unsigned short f2bf(float f) {
  unsigned int u = __float_as_uint(f);
  u = (u + 0x7FFFu + ((u >> 16) & 1u)) >> 16;
  return (unsigned short)u;
}
__device__ __forceinline__ float bf2f(unsigned short u) {
  return __uint_as_float(((unsigned int)u) << 16);
}
__device__ __forceinline__ unsigned int pack2(float a, float b) {
  return (unsigned int)f2bf(a) | ((unsigned int)f2bf(b) << 16);
}

// biased-positive pack: score s is already s+SBIAS (>0), bits monotone as uint
__device__ __forceinline__ unsigned int packB(float sb, int j) {
  return (__float_as_uint(sb) & 0xFFFFF000u) | (unsigned int)j;
}

// ---------------- K0: weight prep (+ sumv zero) -----------------------------
__global__ void k_transpose(const float* __restrict__ w1, const float* __restrict__ lw,
                            const float* __restrict__ w3, const float* __restrict__ w5,
                            const float* __restrict__ wq, const float* __restrict__ wkv,
                            const float* __restrict__ bq, const float* __restrict__ bkv,
                            const float* __restrict__ wproj,
                            unsigned short* __restrict__ w1bf, unsigned short* __restrict__ lwb,
                            float* __restrict__ w3t, float* __restrict__ w5t,
                            unsigned short* __restrict__ wqkvt, float* __restrict__ qkvb,
                            unsigned short* __restrict__ wprojt, float* __restrict__ sumv) {
  int p = blockIdx.x * 256 + threadIdx.x;
  if (p < 256) sumv[p] = 0.0f;
  if (p < 64 * 512) w1bf[p] = f2bf(w1[p]);
  if (p < 64 * 576) {
    int co = p / 576, k = p % 576;
    int tap = k >> 6, ci = k & 63;
    lwb[p] = f2bf(lw[co * 576 + ci * 9 + tap]);
  }
  if (p < 36 * 64) {
    int cin = p & 63, tm = p >> 6;
    int tap = tm >> 2, m = tm & 3;
    w3t[p] = w3[(cin * 4 + m) * 9 + tap];
  }
  if (p < 100 * 64) {
    int cin = p & 63, tm = p >> 6;
    int tap = tm >> 2, m = tm & 3;
    w5t[p] = w5[(cin * 4 + m) * 25 + tap];
  }
  if (p < 192 * 64) {
    int o = p >> 6, i = p & 63;
    float v = (o < 64) ? wq[i * 64 + o] : wkv[i * 128 + (o - 64)];
    wqkvt[p] = f2bf(v);
  }
  if (p < 192) qkvb[p] = (p < 64) ? bq[p] : bkv[p - 64];
  if (p < 64 * 64) {
    int o = p >> 6, i = p & 63;
    wprojt[p] = f2bf(wproj[i * 64 + o]);
  }
}

// ---------------- K1: LN1 + QKV via MFMA (16 tokens/block) + V-sum ----------
__global__ __launch_bounds__(256) void k_ln_qkv(
    const float* __restrict__ x, const float* __restrict__ g1, const float* __restrict__ b1,
    const unsigned short* __restrict__ wqkvt, const float* __restrict__ qkvb,
    unsigned short* __restrict__ q16, unsigned short* __restrict__ k16,
    float* __restrict__ vo, float* __restrict__ sumv) {
  __shared__ __align__(16) unsigned short xnS[16 * XNP];
  int bid = blockIdx.x;
  int b = bid / 196, tile = bid % 196;
  size_t tok0 = (size_t)b * Nv + tile * 16;
  int t = threadIdx.x;
  int w = t >> 6, l = t & 63;
  int tokL = t >> 4;        // 0..15
  int ch0 = (t & 15) * 4;
  size_t tok = tok0 + tokL;
  float v[4];
  *(float4*)v = *(const float4*)&x[tok * 64 + ch0];
  float s = v[0] + v[1] + v[2] + v[3];
  float s2 = v[0] * v[0] + v[1] * v[1] + v[2] * v[2] + v[3] * v[3];
#pragma unroll
  for (int off = 1; off <= 8; off <<= 1) {
    s += __shfl_xor(s, off, 64);
    s2 += __shfl_xor(s2, off, 64);
  }
  float m = s * (1.f / 64.f);
  float rs = rsqrtf(s2 * (1.f / 64.f) - m * m + EPS);
  {
    unsigned int pk[2];
    float a0_ = (v[0] - m) * rs * g1[ch0] + b1[ch0];
    float a1_ = (v[1] - m) * rs * g1[ch0 + 1] + b1[ch0 + 1];
    float a2_ = (v[2] - m) * rs * g1[ch0 + 2] + b1[ch0 + 2];
    float a3_ = (v[3] - m) * rs * g1[ch0 + 3] + b1[ch0 + 3];
    pk[0] = pack2(a0_, a1_);
    pk[1] = pack2(a2_, a3_);
    *(uint2*)&xnS[tokL * XNP + ch0] = *(uint2*)pk;
  }
  __syncthreads();
  int n = l & 15, q = l >> 4;
  const bf16x8 a0 = *(const bf16x8*)&xnS[n * XNP + q * 8];
  const bf16x8 a1 = *(const bf16x8*)&xnS[n * XNP + 32 + q * 8];
  // Q tile j=w
  {
    const unsigned short* wr = &wqkvt[(size_t)(w * 16 + n) * 64];
    bf16x8 b0 = *(const bf16x8*)&wr[q * 8];
    bf16x8 b1_ = *(const bf16x8*)&wr[32 + q * 8];
    f32x4 acc = {0.f, 0.f, 0.f, 0.f};
    acc = __builtin_amdgcn_mfma_f32_16x16x32_bf16(a0, b0, acc, 0, 0, 0);
    acc = __builtin_amdgcn_mfma_f32_16x16x32_bf16(a1, b1_, acc, 0, 0, 0);
    float bias = qkvb[w * 16 + n];
#pragma unroll
    for (int r = 0; r < 4; ++r)
      q16[(tok0 + q * 4 + r) * 64 + w * 16 + n] = f2bf(acc[r] + bias);
  }
  // K tile j=w
  {
    const unsigned short* wr = &wqkvt[(size_t)((w + 4) * 16 + n) * 64];
    bf16x8 b0 = *(const bf16x8*)&wr[q * 8];
    bf16x8 b1_ = *(const bf16x8*)&wr[32 + q * 8];
    f32x4 acc = {0.f, 0.f, 0.f, 0.f};
    acc = __builtin_amdgcn_mfma_f32_16x16x32_bf16(a0, b0, acc, 0, 0, 0);
    acc = __builtin_amdgcn_mfma_f32_16x16x32_bf16(a1, b1_, acc, 0, 0, 0);
    float bias = qkvb[64 + w * 16 + n];
#pragma unroll
    for (int r = 0; r < 4; ++r)
      k16[(tok0 + q * 4 + r) * 64 + w * 16 + n] = f2bf(acc[r] + bias);
  }
  // V tile j=w + fused per-batch column sum
  {
    const unsigned short* wr = &wqkvt[(size_t)((w + 8) * 16 + n) * 64];
    bf16x8 b0 = *(const bf16x8*)&wr[q * 8];
    bf16x8 b1_ = *(const bf16x8*)&wr[32 + q * 8];
    f32x4 acc = {0.f, 0.f, 0.f, 0.f};
    acc = __builtin_amdgcn_mfma_f32_16x16x32_bf16(a0, b0, acc, 0, 0, 0);
    acc = __builtin_amdgcn_mfma_f32_16x16x32_bf16(a1, b1_, acc, 0, 0, 0);
    float bias = qkvb[128 + w * 16 + n];
    float vp = acc[0] + acc[1] + acc[2] + acc[3] + 4.0f * bias;
#pragma unroll
    for (int r = 0; r < 4; ++r)
      vo[(tok0 + q * 4 + r) * 64 + w * 16 + n] = acc[r] + bias;
    vp += __shfl_xor(vp, 16, 64);
    vp += __shfl_xor(vp, 32, 64);
    if (q == 0) atomicAdd(&sumv[b * 64 + w * 16 + n], vp);
  }
}

// ---------------- K2a: pair-batched biased-pack top-8 (8 key splits) --------
// block=128 = 2 independent waves; wave job = (tile, split). Bias trick:
// acc init = SBIAS -> all scores positive -> pack = 1 and_or per score.
// 2 chunks per iteration: two indep MFMA chains, one sort8 + one t8 merge.
__global__ __launch_bounds__(128) void k_attn_topk(
    const unsigned short* __restrict__ q16, const unsigned short* __restrict__ k16,
    unsigned int* __restrict__ top8out) {
  int bid = blockIdx.x;
  int w = threadIdx.x >> 6;
  int lane = threadIdx.x & 63;
  int split = ((bid & 3) << 1) | w;   // 0..7
  int lin = bid >> 2;                 // 0..783
  int b = lin / 196, tile = lin % 196;
  int qbase = b * Nv + tile * 16;
  size_t bN = (size_t)b * Nv;
  int qcol = lane & 15, quad = lane >> 4;
  int quad4 = quad * 4;

  const bf16x8 qf0 = *(const bf16x8*)&q16[((size_t)(qbase + qcol)) * 64 + quad * 8];
  const bf16x8 qf1 = *(const bf16x8*)&q16[((size_t)(qbase + qcol)) * 64 + 32 + quad * 8];

  unsigned int t8[8];
#pragma unroll
  for (int u = 0; u < 8; ++u) t8[u] = 0u;

  int kbase = split * KPS;
  int m = lane & 15;
  const int NCH = 25;  // 24 full chunks + ragged (8 valid keys)

  // prefetch chunks 0, 1
  int r0 = min(kbase + m, Nv - 1);
  int r1 = min(kbase + 16 + m, Nv - 1);
  bf16x8 ka0 = *(const bf16x8*)&k16[(bN + r0) * 64 + quad * 8];
  bf16x8 ka1 = *(const bf16x8*)&k16[(bN + r0) * 64 + 32 + quad * 8];
  bf16x8 kb0 = *(const bf16x8*)&k16[(bN + r1) * 64 + quad * 8];
  bf16x8 kb1 = *(const bf16x8*)&k16[(bN + r1) * 64 + 32 + quad * 8];

#pragma unroll 1
  for (int i = 0; i + 1 < NCH; i += 2) {
    bf16x8 ca0 = ka0, ca1 = ka1, cb0 = kb0, cb1 = kb1;
    int ia = min(i + 2, NCH - 1), ib = min(i + 3, NCH - 1);
    int ra = min(kbase + ia * 16 + m, Nv - 1);
    int rb = min(kbase + ib * 16 + m, Nv - 1);
    ka0 = *(const bf16x8*)&k16[(bN + ra) * 64 + quad * 8];
    ka1 = *(const bf16x8*)&k16[(bN + ra) * 64 + 32 + quad * 8];
    kb0 = *(const bf16x8*)&k16[(bN + rb) * 64 + quad * 8];
    kb1 = *(const bf16x8*)&k16[(bN + rb) * 64 + 32 + quad * 8];

    f32x4 accA = {SBIAS, SBIAS, SBIAS, SBIAS};
    accA = __builtin_amdgcn_mfma_f32_16x16x32_bf16(ca0, qf0, accA, 0, 0, 0);
    accA = __builtin_amdgcn_mfma_f32_16x16x32_bf16(ca1, qf1, accA, 0, 0, 0);
    f32x4 accB = {SBIAS, SBIAS, SBIAS, SBIAS};
    accB = __builtin_amdgcn_mfma_f32_16x16x32_bf16(cb0, qf0, accB, 0, 0, 0);
    accB = __builtin_amdgcn_mfma_f32_16x16x32_bf16(cb1, qf1, accB, 0, 0, 0);

    int jbA = kbase + i * 16 + quad4;
    unsigned int p0 = packB(accA[0], jbA + 0);
    unsigned int p1 = packB(accA[1], jbA + 1);
    unsigned int p2 = packB(accA[2], jbA + 2);
    unsigned int p3 = packB(accA[3], jbA + 3);
    unsigned int q0 = packB(accB[0], jbA + 16);
    unsigned int q1 = packB(accB[1], jbA + 17);
    unsigned int q2 = packB(accB[2], jbA + 18);
    unsigned int q3 = packB(accB[3], jbA + 19);
    // sort4 desc each
    CSWAP(p0, p1); CSWAP(p2, p3); CSWAP(p0, p2); CSWAP(p1, p3); CSWAP(p1, p2);
    CSWAP(q0, q1); CSWAP(q2, q3); CSWAP(q0, q2); CSWAP(q1, q3); CSWAP(q1, q2);
    // bitonic concat -> sorted8 of new scores
    unsigned int u8[8] = {p0, p1, p2, p3, q3, q2, q1, q0};
    BITONIC8(u8);
    // merge into t8
    t8[0] = max(t8[0], u8[7]);
    t8[1] = max(t8[1], u8[6]);
    t8[2] = max(t8[2], u8[5]);
    t8[3] = max(t8[3], u8[4]);
    t8[4] = max(t8[4], u8[3]);
    t8[5] = max(t8[5], u8[2]);
    t8[6] = max(t8[6], u8[1]);
    t8[7] = max(t8[7], u8[0]);
    BITONIC8(t8);
  }
  {  // leftover ragged chunk 24 (keys 384..391 of split: quads 0,1 valid)
    f32x4 accA = {SBIAS, SBIAS, SBIAS, SBIAS};
    accA = __builtin_amdgcn_mfma_f32_16x16x32_bf16(ka0, qf0, accA, 0, 0, 0);
    accA = __builtin_amdgcn_mfma_f32_16x16x32_bf16(ka1, qf1, accA, 0, 0, 0);
    int jl = 384 + quad4;
    bool val = quad < 2;
    unsigned int p0 = val ? packB(accA[0], kbase + jl + 0) : 0u;
    unsigned int p1 = val ? packB(accA[1], kbase + jl + 1) : 0u;
    unsigned int p2 = val ? packB(accA[2], kbase + jl + 2) : 0u;
    unsigned int p3 = val ? packB(accA[3], kbase + jl + 3) : 0u;
    CSWAP(p0, p1); CSWAP(p2, p3); CSWAP(p0, p2); CSWAP(p1, p3); CSWAP(p1, p2);
    t8[4] = max(t8[4], p3);
    t8[5] = max(t8[5], p2);
    t8[6] = max(t8[6], p1);
    t8[7] = max(t8[7], p0);
    BITONIC8(t8);
  }

  // merge across quads (same query col): butterfly xor 16, 32
#pragma unroll
  for (int step = 16; step <= 32; step <<= 1) {
    unsigned int o[8];
#pragma unroll
    for (int i = 0; i < 8; ++i) o[i] = (unsigned int)__shfl_xor((int)t8[i], step, 64);
    unsigned int nw[8];
#pragma unroll
    for (int i = 0; i < 8; ++i) nw[i] = max(t8[i], o[7 - i]);
#pragma unroll
    for (int i = 0; i < 8; ++i) t8[i] = nw[i];
    BITONIC8(t8);
  }
  if (quad == 0) {
    size_t obase = ((size_t)(bN + tile * 16 + qcol)) * 64 + split * 8;
    *(uint4*)&top8out[obase] = make_uint4(t8[0], t8[1], t8[2], t8[3]);
    *(uint4*)&top8out[obase + 4] = make_uint4(t8[4], t8[5], t8[6], t8[7]);
  }
}

// ---- K2b: 8-list merge + PV + local-conv(fused) + proj + LN1 + res + LN2 ---
__global__ __launch_bounds__(256) void k_attn_proj(
    const unsigned int* __restrict__ top8, const float* __restrict__ vg,
    const float* __restrict__ sumv, const float* __restrict__ x,
    const unsigned short* __restrict__ lwb, const float* __restrict__ lb,
    const unsigned short* __restrict__ wprojt, const float* __restrict__ bproj,
    const float* __restrict__ g1, const float* __restrict__ b1,
    const float* __restrict__ g2, const float* __restrict__ b2,
    float* __restrict__ x2, unsigned short* __restrict__ xn2b) {
  __shared__ float kwS[16][8];
  __shared__ int kidxS[16][8];
  __shared__ float invZS[16];
  __shared__ __align__(16) unsigned short imS[16 * LCP];
  __shared__ __align__(16) unsigned short gS[16 * XNP];
  __shared__ float yS[16 * 66];
  int bid = blockIdx.x;
  int b = bid / 196, rem = bid % 196;
  int th = rem / 7, tw = rem % 7;
  int h0 = th * 2, w0 = tw * 8;
  size_t bN = (size_t)b * Nv;
  int t = threadIdx.x;

  // im2col staging from fp32 x (bf16 inline)
  for (int p = t; p < 1152; p += 256) {
    int sub = p & 7, s = p >> 3;
    int tok = s / 9, tap = s % 9;
    int tr = tok >> 3, tc = tok & 7;
    int dh = tap / 3, dw = tap % 3;
    int gh = h0 + tr - 1 + dh, gw = w0 + tc - 1 + dw;
    uint4 uu = {0u, 0u, 0u, 0u};
    if (gh >= 0 && gh < Hh && gw >= 0 && gw < Ww) {
      const float* xp = &x[(bN + gh * Ww + gw) * 64 + sub * 8];
      float4 va = *(const float4*)xp;
      float4 vb = *(const float4*)(xp + 4);
      uu.x = pack2(va.x, va.y);
      uu.y = pack2(va.z, va.w);
      uu.z = pack2(vb.x, vb.y);
      uu.w = pack2(vb.z, vb.w);
    }
    *(uint4*)&imS[tok * LCP + tap * 64 + sub * 8] = uu;
  }

  // Phase A: merge the 8 sorted split-lists per row (t<16, token t local)
  if (t < 16) {
    int gtok = (h0 + (t >> 3)) * Ww + w0 + (t & 7);
    size_t base = (bN + gtok) * 64;
    unsigned int A[8];
#pragma unroll
    for (int i = 0; i < 8; ++i) A[i] = top8[base + i];
#pragma unroll
    for (int h = 1; h < 8; ++h) {
      unsigned int Bb[8];
#pragma unroll
      for (int i = 0; i < 8; ++i) Bb[i] = top8[base + h * 8 + i];
#pragma unroll
      for (int i = 0; i < 8; ++i) A[i] = max(A[i], Bb[7 - i]);
      BITONIC8(A);
    }
    float Z = (float)(Nv - TOPKv);
#pragma unroll
    for (int u = 0; u < 8; ++u) {
      float sb = __uint_as_float(A[u] & 0xFFFFF000u);
      float s = (sb - SBIAS) * SCALE;
      float e = __expf(s);
      kwS[t][u] = e - 1.0f;
      kidxS[t][u] = (int)(A[u] & 0xFFFu);
      Z += e;
    }
    invZS[t] = 1.0f / Z;
  }
  __syncthreads();

  int w = t >> 6, l = t & 63;
  int n = l & 15, q = l >> 4;

  // local conv MFMA (18 per wave), result in registers
  f32x4 lacc = {0.f, 0.f, 0.f, 0.f};
  {
    const unsigned short* lwrow = &lwb[(size_t)(w * 16 + n) * 576];
#pragma unroll 6
    for (int kk = 0; kk < 18; ++kk) {
      bf16x8 af = *(const bf16x8*)&imS[n * LCP + kk * 32 + q * 8];
      bf16x8 bfr = *(const bf16x8*)&lwrow[kk * 32 + q * 8];
      lacc = __builtin_amdgcn_mfma_f32_16x16x32_bf16(af, bfr, lacc, 0, 0, 0);
    }
  }
  float lbias = lb[w * 16 + n];

  // Phase B: g = (sumv + sum_top8 (e^s-1) v)/Z -> gS (bf16)
  {
    int c = t & 63, rg = t >> 6;
    float sv = sumv[b * 64 + c];
#pragma unroll
    for (int rr = 0; rr < 4; ++rr) {
      int tokL = rg * 4 + rr;
      float acc = sv;
#pragma unroll
      for (int u = 0; u < 8; ++u)
        acc += kwS[tokL][u] * vg[(bN + kidxS[tokL][u]) * 64 + c];
      gS[tokL * XNP + c] = f2bf(acc * invZS[tokL]);
    }
  }
  __syncthreads();

  // Phase C: proj GEMM + add local conv, y -> yS
  {
    const bf16x8 a0 = *(const bf16x8*)&gS[n * XNP + q * 8];
    const bf16x8 a1 = *(const bf16x8*)&gS[n * XNP + 32 + q * 8];
    const unsigned short* wr = &wprojt[(size_t)(w * 16 + n) * 64];
    bf16x8 b0 = *(const bf16x8*)&wr[q * 8];
    bf16x8 b1_ = *(const bf16x8*)&wr[32 + q * 8];
    f32x4 acc = {0.f, 0.f, 0.f, 0.f};
    acc = __builtin_amdgcn_mfma_f32_16x16x32_bf16(a0, b0, acc, 0, 0, 0);
    acc = __builtin_amdgcn_mfma_f32_16x16x32_bf16(a1, b1_, acc, 0, 0, 0);
    float bias = bproj[w * 16 + n];
#pragma unroll
    for (int r = 0; r < 4; ++r)
      yS[(q * 4 + r) * 66 + w * 16 + n] = acc[r] + bias + lacc[r] + lbias;
  }
  __syncthreads();

  // Phase D: LN1 -> residual -> LN2 (16-lane group per token, 4 ch each)
  int tokL = t >> 4;
  int ch0 = (t & 15) * 4;
  size_t tok = bN + (size_t)(h0 + (tokL >> 3)) * Ww + w0 + (tokL & 7);
  float y[4];
#pragma unroll
  for (int i = 0; i < 4; ++i) y[i] = yS[tokL * 66 + ch0 + i];
  float s = y[0] + y[1] + y[2] + y[3];
  float s2 = y[0] * y[0] + y[1] * y[1] + y[2] * y[2] + y[3] * y[3];
#pragma unroll
  for (int off = 1; off <= 8; off <<= 1) {
    s += __shfl_xor(s, off, 64);
    s2 += __shfl_xor(s2, off, 64);
  }
  float m1 = s * (1.f / 64.f);
  float rs1 = rsqrtf(s2 * (1.f / 64.f) - m1 * m1 + EPS);
  float xv[4];
  *(float4*)xv = *(const float4*)&x[tok * 64 + ch0];
  float x2v[4];
  float t_s = 0.f, t_s2 = 0.f;
#pragma unroll
  for (int i = 0; i < 4; ++i) {
    float t1 = (y[i] - m1) * rs1 * g1[ch0 + i] + b1[ch0 + i];
    x2v[i] = xv[i] + t1;
    t_s += x2v[i];
    t_s2 += x2v[i] * x2v[i];
  }
#pragma unroll
  for (int off = 1; off <= 8; off <<= 1) {
    t_s += __shfl_xor(t_s, off, 64);
    t_s2 += __shfl_xor(t_s2, off, 64);
  }
  float m2 = t_s * (1.f / 64.f);
  float rs2 = rsqrtf(t_s2 * (1.f / 64.f) - m2 * m2 + EPS);
  *(float4*)&x2[tok * 64 + ch0] = *(float4*)x2v;
  unsigned int pk[2];
  {
    float a0_ = (x2v[0] - m2) * rs2 * g2[ch0] + b2[ch0];
    float a1_ = (x2v[1] - m2) * rs2 * g2[ch0 + 1] + b2[ch0 + 1];
    float a2_ = (x2v[2] - m2) * rs2 * g2[ch0 + 2] + b2[ch0 + 2];
    float a3_ = (x2v[3] - m2) * rs2 * g2[ch0 + 3] + b2[ch0 + 3];
    pk[0] = pack2(a0_, a1_);
    pk[1] = pack2(a2_, a3_);
  }
  *(uint2*)&xn2b[tok * 64 + ch0] = *(uint2*)pk;
}

// ---------------- K5: MSFN — depthwise in regs, 1x1 via MFMA ----------------
__global__ __launch_bounds__(256) void k_msfn(
    const unsigned short* __restrict__ xn2b, const float* __restrict__ x2,
    const float* __restrict__ w3t, const float* __restrict__ b3,
    const float* __restrict__ w5t, const float* __restrict__ b5,
    const unsigned short* __restrict__ w1bf, const float* __restrict__ b1,
    float* __restrict__ out) {
  __shared__ __align__(16) unsigned short xtS[6 * 12 * 64];
  __shared__ __align__(16) unsigned short tsS[16 * TSP];

  int bid = blockIdx.x;
  int b = bid / 196;
  int rem = bid % 196;
  int th = rem / 7, tw = rem % 7;
  int h0 = th * 2, w0 = tw * 8;
  size_t bN = (size_t)b * Nv;
  int t = threadIdx.x;

  unsigned int* xtU = (unsigned int*)xtS;
  for (int p = t; p < 6 * 12 * 32; p += 256) {
    int cp = p & 31, rc = p >> 5;
    int r = rc / 12, cc = rc % 12;
    int gh = h0 - 2 + r, gw = w0 - 2 + cc;
    unsigned int v = 0;
    if (gh >= 0 && gh < Hh && gw >= 0 && gw < Ww)
      v = *(const unsigned int*)&xn2b[(bN + gh * Ww + gw) * 64 + cp * 2];
    xtU[rc * 32 + cp] = v;
  }
  __syncthreads();

  int cin = t & 63, tg = t >> 6;
  int tr = tg >> 1, tc0 = (tg & 1) * 4;
  float win[5][8];
#pragma unroll
  for (int r = 0; r < 5; ++r)
#pragma unroll
    for (int c = 0; c < 8; ++c)
      win[r][c] = bf2f(xtS[((tr + r) * 12 + tc0 + c) * 64 + cin]);

  unsigned int* tsU = (unsigned int*)tsS;
#pragma unroll 1
  for (int m2 = 0; m2 < 4; m2 += 2) {
    float a3[2][9], a5[2][25], bb3[2], bb5[2];
#pragma unroll
    for (int mm = 0; mm < 2; ++mm) {
      int m = m2 + mm;
#pragma unroll
      for (int tap = 0; tap < 9; ++tap) a3[mm][tap] = w3t[(tap * 4 + m) * 64 + cin];
#pragma unroll
      for (int tap = 0; tap < 25; ++tap) a5[mm][tap] = w5t[(tap * 4 + m) * 64 + cin];
      bb3[mm] = b3[cin * 4 + m];
      bb5[mm] = b5[cin * 4 + m];
    }
#pragma unroll
    for (int tk = 0; tk < 4; ++tk) {
      int tok = tg * 4 + tk;
      unsigned int p3 = 0, p5 = 0;
#pragma unroll
      for (int mm = 0; mm < 2; ++mm) {
        float acc3 = bb3[mm];
#pragma unroll
        for (int kh = 0; kh < 3; ++kh)
#pragma unroll
          for (int kw2 = 0; kw2 < 3; ++kw2)
            acc3 += win[1 + kh][tk + 1 + kw2] * a3[mm][kh * 3 + kw2];
        float acc5 = bb5[mm];
#pragma unroll
        for (int kh = 0; kh < 5; ++kh)
#pragma unroll
          for (int kw2 = 0; kw2 < 5; ++kw2)
            acc5 += win[kh][tk + kw2] * a5[mm][kh * 5 + kw2];
        p3 |= (unsigned int)f2bf(acc3) << (16 * mm);
        p5 |= (unsigned int)f2bf(acc5) << (16 * mm);
      }
      tsU[(tok * TSP + cin * 4 + m2) >> 1] = p3;
      tsU[(tok * TSP + 256 + cin * 4 + m2) >> 1] = p5;
    }
  }
  __syncthreads();

  int wv = tg, lane = t & 63;
  int n16 = lane & 15, quad = lane >> 4;
  const unsigned short* wrow = &w1bf[(size_t)(wv * 16 + n16) * 512];
  f32x4 acc = {0.f, 0.f, 0.f, 0.f};
#pragma unroll 4
  for (int kk = 0; kk < 16; ++kk) {
    bf16x8 af = *(const bf16x8*)&tsS[n16 * TSP + kk * 32 + quad * 8];
    bf16x8 bfr = *(const bf16x8*)&wrow[kk * 32 + quad * 8];
    acc = __builtin_amdgcn_mfma_f32_16x16x32_bf16(af, bfr, acc, 0, 0, 0);
  }
  float bias = b1[wv * 16 + n16];
#pragma unroll
  for (int r = 0; r < 4; ++r) {
    int tok = quad * 4 + r;
    int trr = tok >> 3, tcc = tok & 7;
    size_t idx = (bN + (size_t)(h0 + trr) * Ww + w0 + tcc) * 64 + wv * 16 + n16;
    out[idx] = x2[idx] + acc[r] + bias;
  }
}

extern "C" void kernel_launch(void* const* d_in, const int* in_sizes, int n_in,
                              void* d_out, int out_size, void* d_ws, size_t ws_size,
                              hipStream_t stream) {
  const float* x = (const float*)d_in[0];
  const float* n1g = (const float*)d_in[1];
  const float* n1b = (const float*)d_in[2];
  const float* wq = (const float*)d_in[3];
  const float* bq = (const float*)d_in[4];
  const float* wkv = (const float*)d_in[5];
  const float* bkv = (const float*)d_in[6];
  const float* wproj = (const float*)d_in[7];
  const float* bproj = (const float*)d_in[8];
  const float* lw = (const float*)d_in[9];
  const float* lb = (const float*)d_in[10];
  const float* n2g = (const float*)d_in[11];
  const float* n2b = (const float*)d_in[12];
  const float* w3 = (const float*)d_in[13];
  const float* b3 = (const float*)d_in[14];
  const float* w5 = (const float*)d_in[15];
  const float* b5 = (const float*)d_in[16];
  const float* w1 = (const float*)d_in[17];
  const float* b1 = (const float*)d_in[18];
  float* out = (float*)d_out;

  float* ws = (float*)d_ws;
  const size_t TOK = (size_t)Bv * Nv * Cv;  // 802816
  float* vb = ws;
  float* sumv = vb + TOK;            // 256
  float* x2 = sumv + 256;
  float* w3t = x2 + TOK;             // 2304
  float* w5t = w3t + 2304;           // 6400
  float* qkvb = w5t + 6400;          // 192
  unsigned short* q16 = (unsigned short*)(qkvb + 192);
  unsigned short* k16 = q16 + TOK;
  unsigned short* xn2b = k16 + TOK;
  unsigned short* w1bf = xn2b + TOK;       // 64*512
  unsigned short* lwb = w1bf + 64 * 512;   // 64*576
  unsigned short* wqkvt = lwb + 64 * 576;  // 192*64
  unsigned short* wprojt = wqkvt + 192 * 64;  // 64*64
  unsigned int* top8ws = (unsigned int*)(wprojt + 64 * 64 + 64);  // 12544*64 uints

  k_transpose<<<144, 256, 0, stream>>>(w1, lw, w3, w5, wq, wkv, bq, bkv, wproj,
                                       w1bf, lwb, w3t, w5t, wqkvt, qkvb, wprojt, sumv);
  k_ln_qkv<<<Bv * 196, 256, 0, stream>>>(x, n1g, n1b, wqkvt, qkvb, q16, k16, vb, sumv);
  k_attn_topk<<<Bv * 196 * 4, 128, 0, stream>>>(q16, k16, top8ws);
  k_attn_proj<<<Bv * 196, 256, 0, stream>>>(top8ws, vb, sumv, x, lwb, lb, wprojt, bproj,
                                            n1g, n1b, n2g, n2b, x2, xn2b);
  k_msfn<<<Bv * 196, 256, 0, stream>>>(xn2b, x2, w3t, b3, w5t, b5, w1bf, b1, out);
}

// Round 13
// 185.007 us; speedup vs baseline: 1.0162x; 1.0162x over previous
//
#include <hip/hip_runtime.h>
#include <math.h>

#define Bv 4
#define Nv 3136
#define Cv 64
#define Hh 56
#define Ww 56
#define HIDv 256
#define TOPKv 8
#define TSP 520   // msfn ts row pitch (bf16): dword pitch % 32 == 4 -> conflict-free b128
#define LCP 584   // im2col row pitch (576+8): same property
#define XNP 72    // ln/proj LDS bf16 row pitch (64+8): dword pitch 36 % 32 == 4
#define KSPL 8    // key splits in k_attn_topk
#define KPS 392   // keys per split (3136/8)

constexpr float SCALE = 0.125f;   // d^-0.5, d=64
constexpr float EPS = 1e-5f;
constexpr float SBIAS = 128.0f;   // score bias: all packed scores positive

typedef short bf16x8 __attribute__((ext_vector_type(8)));
typedef float f32x4 __attribute__((ext_vector_type(4)));

#define CSWAP(a, b) { unsigned int _hi = max(a, b); unsigned int _lo = min(a, b); a = _hi; b = _lo; }
// descending bitonic clean of 8 (input: bitonic), 3 stages
#define BITONIC8(T) \
  CSWAP(T[0], T[4]); CSWAP(T[1], T[5]); CSWAP(T[2], T[6]); CSWAP(T[3], T[7]); \
  CSWAP(T[0], T[2]); CSWAP(T[1], T[3]); CSWAP(T[4], T[6]); CSWAP(T[5], T[7]); \
  CSWAP(T[0], T[1]); CSWAP(T[2], T[3]); CSWAP(T[4], T[5]); CSWAP(T[6], T[7]);

__device__ __forceinline__ unsigned short f2bf(float f) {
  unsigned int u = __float_as_uint(f);
  u = (u + 0x7FFFu + ((u >> 16) & 1u)) >> 16;
  return (unsigned short)u;
}
__device__ __forceinline__ float bf2f(unsigned short u) {
  return __uint_as_float(((unsigned int)u) << 16);
}
__device__ __forceinline__ unsigned int pack2(float a, float b) {
  return (unsigned int)f2bf(a) | ((unsigned int)f2bf(b) << 16);
}

// biased-positive pack: score s is already s+SBIAS (>0), bits monotone as uint
__device__ __forceinline__ unsigned int packB(float sb, int j) {
  return (__float_as_uint(sb) & 0xFFFFF000u) | (unsigned int)j;
}

// ---------------- K0: weight prep (+ sumv zero) -----------------------------
__global__ void k_transpose(const float* __restrict__ w1, const float* __restrict__ lw,
                            const float* __restrict__ w3, const float* __restrict__ w5,
                            const float* __restrict__ wq, const float* __restrict__ wkv,
                            const float* __restrict__ bq, const float* __restrict__ bkv,
                            const float* __restrict__ wproj,
                            unsigned short* __restrict__ w1bf, unsigned short* __restrict__ lwb,
                            float* __restrict__ w3t, float* __restrict__ w5t,
                            unsigned short* __restrict__ wqkvt, float* __restrict__ qkvb,
                            unsigned short* __restrict__ wprojt, float* __restrict__ sumv) {
  int p = blockIdx.x * 256 + threadIdx.x;
  if (p < 256) sumv[p] = 0.0f;
  if (p < 64 * 512) w1bf[p] = f2bf(w1[p]);
  if (p < 64 * 576) {
    int co = p / 576, k = p % 576;
    int tap = k >> 6, ci = k & 63;
    lwb[p] = f2bf(lw[co * 576 + ci * 9 + tap]);
  }
  if (p < 36 * 64) {
    int cin = p & 63, tm = p >> 6;
    int tap = tm >> 2, m = tm & 3;
    w3t[p] = w3[(cin * 4 + m) * 9 + tap];
  }
  if (p < 100 * 64) {
    int cin = p & 63, tm = p >> 6;
    int tap = tm >> 2, m = tm & 3;
    w5t[p] = w5[(cin * 4 + m) * 25 + tap];
  }
  if (p < 192 * 64) {
    int o = p >> 6, i = p & 63;
    float v = (o < 64) ? wq[i * 64 + o] : wkv[i * 128 + (o - 64)];
    wqkvt[p] = f2bf(v);
  }
  if (p < 192) qkvb[p] = (p < 64) ? bq[p] : bkv[p - 64];
  if (p < 64 * 64) {
    int o = p >> 6, i = p & 63;
    wprojt[p] = f2bf(wproj[i * 64 + o]);
  }
}

// ---------------- K1: LN1 + QKV via MFMA (16 tokens/block) + V-sum ----------
__global__ __launch_bounds__(256) void k_ln_qkv(
    const float* __restrict__ x, const float* __restrict__ g1, const float* __restrict__ b1,
    const unsigned short* __restrict__ wqkvt, const float* __restrict__ qkvb,
    unsigned short* __restrict__ q16, unsigned short* __restrict__ k16,
    float* __restrict__ vo, float* __restrict__ sumv) {
  __shared__ __align__(16) unsigned short xnS[16 * XNP];
  int bid = blockIdx.x;
  int b = bid / 196, tile = bid % 196;
  size_t tok0 = (size_t)b * Nv + tile * 16;
  int t = threadIdx.x;
  int w = t >> 6, l = t & 63;
  int tokL = t >> 4;        // 0..15
  int ch0 = (t & 15) * 4;
  size_t tok = tok0 + tokL;
  float v[4];
  *(float4*)v = *(const float4*)&x[tok * 64 + ch0];
  float s = v[0] + v[1] + v[2] + v[3];
  float s2 = v[0] * v[0] + v[1] * v[1] + v[2] * v[2] + v[3] * v[3];
#pragma unroll
  for (int off = 1; off <= 8; off <<= 1) {
    s += __shfl_xor(s, off, 64);
    s2 += __shfl_xor(s2, off, 64);
  }
  float m = s * (1.f / 64.f);
  float rs = rsqrtf(s2 * (1.f / 64.f) - m * m + EPS);
  {
    unsigned int pk[2];
    float a0_ = (v[0] - m) * rs * g1[ch0] + b1[ch0];
    float a1_ = (v[1] - m) * rs * g1[ch0 + 1] + b1[ch0 + 1];
    float a2_ = (v[2] - m) * rs * g1[ch0 + 2] + b1[ch0 + 2];
    float a3_ = (v[3] - m) * rs * g1[ch0 + 3] + b1[ch0 + 3];
    pk[0] = pack2(a0_, a1_);
    pk[1] = pack2(a2_, a3_);
    *(uint2*)&xnS[tokL * XNP + ch0] = *(uint2*)pk;
  }
  __syncthreads();
  int n = l & 15, q = l >> 4;
  const bf16x8 a0 = *(const bf16x8*)&xnS[n * XNP + q * 8];
  const bf16x8 a1 = *(const bf16x8*)&xnS[n * XNP + 32 + q * 8];
  // Q tile j=w
  {
    const unsigned short* wr = &wqkvt[(size_t)(w * 16 + n) * 64];
    bf16x8 b0 = *(const bf16x8*)&wr[q * 8];
    bf16x8 b1_ = *(const bf16x8*)&wr[32 + q * 8];
    f32x4 acc = {0.f, 0.f, 0.f, 0.f};
    acc = __builtin_amdgcn_mfma_f32_16x16x32_bf16(a0, b0, acc, 0, 0, 0);
    acc = __builtin_amdgcn_mfma_f32_16x16x32_bf16(a1, b1_, acc, 0, 0, 0);
    float bias = qkvb[w * 16 + n];
#pragma unroll
    for (int r = 0; r < 4; ++r)
      q16[(tok0 + q * 4 + r) * 64 + w * 16 + n] = f2bf(acc[r] + bias);
  }
  // K tile j=w
  {
    const unsigned short* wr = &wqkvt[(size_t)((w + 4) * 16 + n) * 64];
    bf16x8 b0 = *(const bf16x8*)&wr[q * 8];
    bf16x8 b1_ = *(const bf16x8*)&wr[32 + q * 8];
    f32x4 acc = {0.f, 0.f, 0.f, 0.f};
    acc = __builtin_amdgcn_mfma_f32_16x16x32_bf16(a0, b0, acc, 0, 0, 0);
    acc = __builtin_amdgcn_mfma_f32_16x16x32_bf16(a1, b1_, acc, 0, 0, 0);
    float bias = qkvb[64 + w * 16 + n];
#pragma unroll
    for (int r = 0; r < 4; ++r)
      k16[(tok0 + q * 4 + r) * 64 + w * 16 + n] = f2bf(acc[r] + bias);
  }
  // V tile j=w + fused per-batch column sum
  {
    const unsigned short* wr = &wqkvt[(size_t)((w + 8) * 16 + n) * 64];
    bf16x8 b0 = *(const bf16x8*)&wr[q * 8];
    bf16x8 b1_ = *(const bf16x8*)&wr[32 + q * 8];
    f32x4 acc = {0.f, 0.f, 0.f, 0.f};
    acc = __builtin_amdgcn_mfma_f32_16x16x32_bf16(a0, b0, acc, 0, 0, 0);
    acc = __builtin_amdgcn_mfma_f32_16x16x32_bf16(a1, b1_, acc, 0, 0, 0);
    float bias = qkvb[128 + w * 16 + n];
    float vp = acc[0] + acc[1] + acc[2] + acc[3] + 4.0f * bias;
#pragma unroll
    for (int r = 0; r < 4; ++r)
      vo[(tok0 + q * 4 + r) * 64 + w * 16 + n] = acc[r] + bias;
    vp += __shfl_xor(vp, 16, 64);
    vp += __shfl_xor(vp, 32, 64);
    if (q == 0) atomicAdd(&sumv[b * 64 + w * 16 + n], vp);
  }
}

// ---------------- K2a: strided-offset pair-batched top-8 (8 key splits) -----
// block=128 = 2 independent waves; wave job = (tile, split). Clampless
// steady-state loop: one running 32-bit byte offset (+4096/pair), companion
// loads at immediate offsets (+64/+2048/+2112). Tail iterations peeled.
// Tail reads past split end land in adjacent ws buffers (masked in pack).
__global__ __launch_bounds__(128) void k_attn_topk(
    const unsigned short* __restrict__ q16, const unsigned short* __restrict__ k16,
    unsigned int* __restrict__ top8out) {
  int bid = blockIdx.x;
  int w = threadIdx.x >> 6;
  int lane = threadIdx.x & 63;
  int split = ((bid & 3) << 1) | w;   // 0..7
  int lin = bid >> 2;                 // 0..783
  int b = lin / 196, tile = lin % 196;
  int qbase = b * Nv + tile * 16;
  size_t bN = (size_t)b * Nv;
  int qcol = lane & 15, quad = lane >> 4;
  int quad4 = quad * 4;

  const bf16x8 qf0 = *(const bf16x8*)&q16[((size_t)(qbase + qcol)) * 64 + quad * 8];
  const bf16x8 qf1 = *(const bf16x8*)&q16[((size_t)(qbase + qcol)) * 64 + 32 + quad * 8];

  unsigned int t8[8];
#pragma unroll
  for (int u = 0; u < 8; ++u) t8[u] = 0u;

  int kbase = split * KPS;
  int m = lane & 15;
  const char* kbp = (const char*)(k16 + bN * 64);
  unsigned int offA = (unsigned int)((kbase + m) * 128 + quad * 16);
  int jbA = kbase + quad4;

  // prefetch chunks 0,1
  bf16x8 ka0 = *(const bf16x8*)(kbp + offA);
  bf16x8 ka1 = *(const bf16x8*)(kbp + offA + 64);
  bf16x8 kb0 = *(const bf16x8*)(kbp + offA + 2048);
  bf16x8 kb1 = *(const bf16x8*)(kbp + offA + 2112);
  offA += 4096;

#pragma unroll 1
  for (int it = 0; it < 11; ++it) {  // chunks 0..21, clampless
    bf16x8 ca0 = ka0, ca1 = ka1, cb0 = kb0, cb1 = kb1;
    ka0 = *(const bf16x8*)(kbp + offA);
    ka1 = *(const bf16x8*)(kbp + offA + 64);
    kb0 = *(const bf16x8*)(kbp + offA + 2048);
    kb1 = *(const bf16x8*)(kbp + offA + 2112);
    offA += 4096;

    f32x4 accA = {SBIAS, SBIAS, SBIAS, SBIAS};
    accA = __builtin_amdgcn_mfma_f32_16x16x32_bf16(ca0, qf0, accA, 0, 0, 0);
    accA = __builtin_amdgcn_mfma_f32_16x16x32_bf16(ca1, qf1, accA, 0, 0, 0);
    f32x4 accB = {SBIAS, SBIAS, SBIAS, SBIAS};
    accB = __builtin_amdgcn_mfma_f32_16x16x32_bf16(cb0, qf0, accB, 0, 0, 0);
    accB = __builtin_amdgcn_mfma_f32_16x16x32_bf16(cb1, qf1, accB, 0, 0, 0);

    unsigned int p0 = packB(accA[0], jbA + 0);
    unsigned int p1 = packB(accA[1], jbA + 1);
    unsigned int p2 = packB(accA[2], jbA + 2);
    unsigned int p3 = packB(accA[3], jbA + 3);
    unsigned int q0 = packB(accB[0], jbA + 16);
    unsigned int q1 = packB(accB[1], jbA + 17);
    unsigned int q2 = packB(accB[2], jbA + 18);
    unsigned int q3 = packB(accB[3], jbA + 19);
    jbA += 32;
    CSWAP(p0, p1); CSWAP(p2, p3); CSWAP(p0, p2); CSWAP(p1, p3); CSWAP(p1, p2);
    CSWAP(q0, q1); CSWAP(q2, q3); CSWAP(q0, q2); CSWAP(q1, q3); CSWAP(q1, q2);
    unsigned int u8[8] = {p0, p1, p2, p3, q3, q2, q1, q0};
    BITONIC8(u8);
    t8[0] = max(t8[0], u8[7]);
    t8[1] = max(t8[1], u8[6]);
    t8[2] = max(t8[2], u8[5]);
    t8[3] = max(t8[3], u8[4]);
    t8[4] = max(t8[4], u8[3]);
    t8[5] = max(t8[5], u8[2]);
    t8[6] = max(t8[6], u8[1]);
    t8[7] = max(t8[7], u8[0]);
    BITONIC8(t8);
  }

  {  // peeled pair: chunks 22,23; prefetch chunk 24 (chain A only)
    bf16x8 ca0 = ka0, ca1 = ka1, cb0 = kb0, cb1 = kb1;
    ka0 = *(const bf16x8*)(kbp + offA);
    ka1 = *(const bf16x8*)(kbp + offA + 64);

    f32x4 accA = {SBIAS, SBIAS, SBIAS, SBIAS};
    accA = __builtin_amdgcn_mfma_f32_16x16x32_bf16(ca0, qf0, accA, 0, 0, 0);
    accA = __builtin_amdgcn_mfma_f32_16x16x32_bf16(ca1, qf1, accA, 0, 0, 0);
    f32x4 accB = {SBIAS, SBIAS, SBIAS, SBIAS};
    accB = __builtin_amdgcn_mfma_f32_16x16x32_bf16(cb0, qf0, accB, 0, 0, 0);
    accB = __builtin_amdgcn_mfma_f32_16x16x32_bf16(cb1, qf1, accB, 0, 0, 0);

    unsigned int p0 = packB(accA[0], jbA + 0);
    unsigned int p1 = packB(accA[1], jbA + 1);
    unsigned int p2 = packB(accA[2], jbA + 2);
    unsigned int p3 = packB(accA[3], jbA + 3);
    unsigned int q0 = packB(accB[0], jbA + 16);
    unsigned int q1 = packB(accB[1], jbA + 17);
    unsigned int q2 = packB(accB[2], jbA + 18);
    unsigned int q3 = packB(accB[3], jbA + 19);
    jbA += 32;
    CSWAP(p0, p1); CSWAP(p2, p3); CSWAP(p0, p2); CSWAP(p1, p3); CSWAP(p1, p2);
    CSWAP(q0, q1); CSWAP(q2, q3); CSWAP(q0, q2); CSWAP(q1, q3); CSWAP(q1, q2);
    unsigned int u8[8] = {p0, p1, p2, p3, q3, q2, q1, q0};
    BITONIC8(u8);
    t8[0] = max(t8[0], u8[7]);
    t8[1] = max(t8[1], u8[6]);
    t8[2] = max(t8[2], u8[5]);
    t8[3] = max(t8[3], u8[4]);
    t8[4] = max(t8[4], u8[3]);
    t8[5] = max(t8[5], u8[2]);
    t8[6] = max(t8[6], u8[1]);
    t8[7] = max(t8[7], u8[0]);
    BITONIC8(t8);
  }

  {  // ragged chunk 24: keys 384..391 of split valid (quads 0,1)
    f32x4 accA = {SBIAS, SBIAS, SBIAS, SBIAS};
    accA = __builtin_amdgcn_mfma_f32_16x16x32_bf16(ka0, qf0, accA, 0, 0, 0);
    accA = __builtin_amdgcn_mfma_f32_16x16x32_bf16(ka1, qf1, accA, 0, 0, 0);
    bool val = quad < 2;
    unsigned int p0 = val ? packB(accA[0], jbA + 0) : 0u;
    unsigned int p1 = val ? packB(accA[1], jbA + 1) : 0u;
    unsigned int p2 = val ? packB(accA[2], jbA + 2) : 0u;
    unsigned int p3 = val ? packB(accA[3], jbA + 3) : 0u;
    CSWAP(p0, p1); CSWAP(p2, p3); CSWAP(p0, p2); CSWAP(p1, p3); CSWAP(p1, p2);
    t8[4] = max(t8[4], p3);
    t8[5] = max(t8[5], p2);
    t8[6] = max(t8[6], p1);
    t8[7] = max(t8[7], p0);
    BITONIC8(t8);
  }

  // merge across quads (same query col): butterfly xor 16, 32
#pragma unroll
  for (int step = 16; step <= 32; step <<= 1) {
    unsigned int o[8];
#pragma unroll
    for (int i = 0; i < 8; ++i) o[i] = (unsigned int)__shfl_xor((int)t8[i], step, 64);
    unsigned int nw[8];
#pragma unroll
    for (int i = 0; i < 8; ++i) nw[i] = max(t8[i], o[7 - i]);
#pragma unroll
    for (int i = 0; i < 8; ++i) t8[i] = nw[i];
    BITONIC8(t8);
  }
  if (quad == 0) {
    size_t obase = ((size_t)(bN + tile * 16 + qcol)) * 64 + split * 8;
    *(uint4*)&top8out[obase] = make_uint4(t8[0], t8[1], t8[2], t8[3]);
    *(uint4*)&top8out[obase + 4] = make_uint4(t8[4], t8[5], t8[6], t8[7]);
  }
}

// ---- K2b: 8-list merge + PV + local-conv(fused) + proj + LN1 + res + LN2 ---
__global__ __launch_bounds__(256) void k_attn_proj(
    const unsigned int* __restrict__ top8, const float* __restrict__ vg,
    const float* __restrict__ sumv, const float* __restrict__ x,
    const unsigned short* __restrict__ lwb, const float* __restrict__ lb,
    const unsigned short* __restrict__ wprojt, const float* __restrict__ bproj,
    const float* __restrict__ g1, const float* __restrict__ b1,
    const float* __restrict__ g2, const float* __restrict__ b2,
    float* __restrict__ x2, unsigned short* __restrict__ xn2b) {
  __shared__ float kwS[16][8];
  __shared__ int kidxS[16][8];
  __shared__ float invZS[16];
  __shared__ __align__(16) unsigned short imS[16 * LCP];
  __shared__ __align__(16) unsigned short gS[16 * XNP];
  __shared__ float yS[16 * 66];
  int bid = blockIdx.x;
  int b = bid / 196, rem = bid % 196;
  int th = rem / 7, tw = rem % 7;
  int h0 = th * 2, w0 = tw * 8;
  size_t bN = (size_t)b * Nv;
  int t = threadIdx.x;

  // im2col staging from fp32 x (bf16 inline)
  for (int p = t; p < 1152; p += 256) {
    int sub = p & 7, s = p >> 3;
    int tok = s / 9, tap = s % 9;
    int tr = tok >> 3, tc = tok & 7;
    int dh = tap / 3, dw = tap % 3;
    int gh = h0 + tr - 1 + dh, gw = w0 + tc - 1 + dw;
    uint4 uu = {0u, 0u, 0u, 0u};
    if (gh >= 0 && gh < Hh && gw >= 0 && gw < Ww) {
      const float* xp = &x[(bN + gh * Ww + gw) * 64 + sub * 8];
      float4 va = *(const float4*)xp;
      float4 vb = *(const float4*)(xp + 4);
      uu.x = pack2(va.x, va.y);
      uu.y = pack2(va.z, va.w);
      uu.z = pack2(vb.x, vb.y);
      uu.w = pack2(vb.z, vb.w);
    }
    *(uint4*)&imS[tok * LCP + tap * 64 + sub * 8] = uu;
  }

  // Phase A: merge the 8 sorted split-lists per row (t<16, token t local)
  if (t < 16) {
    int gtok = (h0 + (t >> 3)) * Ww + w0 + (t & 7);
    size_t base = (bN + gtok) * 64;
    unsigned int A[8];
#pragma unroll
    for (int i = 0; i < 8; ++i) A[i] = top8[base + i];
#pragma unroll
    for (int h = 1; h < 8; ++h) {
      unsigned int Bb[8];
#pragma unroll
      for (int i = 0; i < 8; ++i) Bb[i] = top8[base + h * 8 + i];
#pragma unroll
      for (int i = 0; i < 8; ++i) A[i] = max(A[i], Bb[7 - i]);
      BITONIC8(A);
    }
    float Z = (float)(Nv - TOPKv);
#pragma unroll
    for (int u = 0; u < 8; ++u) {
      float sb = __uint_as_float(A[u] & 0xFFFFF000u);
      float s = (sb - SBIAS) * SCALE;
      float e = __expf(s);
      kwS[t][u] = e - 1.0f;
      kidxS[t][u] = (int)(A[u] & 0xFFFu);
      Z += e;
    }
    invZS[t] = 1.0f / Z;
  }
  __syncthreads();

  int w = t >> 6, l = t & 63;
  int n = l & 15, q = l >> 4;

  // local conv MFMA (18 per wave), result in registers
  f32x4 lacc = {0.f, 0.f, 0.f, 0.f};
  {
    const unsigned short* lwrow = &lwb[(size_t)(w * 16 + n) * 576];
#pragma unroll 6
    for (int kk = 0; kk < 18; ++kk) {
      bf16x8 af = *(const bf16x8*)&imS[n * LCP + kk * 32 + q * 8];
      bf16x8 bfr = *(const bf16x8*)&lwrow[kk * 32 + q * 8];
      lacc = __builtin_amdgcn_mfma_f32_16x16x32_bf16(af, bfr, lacc, 0, 0, 0);
    }
  }
  float lbias = lb[w * 16 + n];

  // Phase B: g = (sumv + sum_top8 (e^s-1) v)/Z -> gS (bf16)
  {
    int c = t & 63, rg = t >> 6;
    float sv = sumv[b * 64 + c];
#pragma unroll
    for (int rr = 0; rr < 4; ++rr) {
      int tokL = rg * 4 + rr;
      float acc = sv;
#pragma unroll
      for (int u = 0; u < 8; ++u)
        acc += kwS[tokL][u] * vg[(bN + kidxS[tokL][u]) * 64 + c];
      gS[tokL * XNP + c] = f2bf(acc * invZS[tokL]);
    }
  }
  __syncthreads();

  // Phase C: proj GEMM + add local conv, y -> yS
  {
    const bf16x8 a0 = *(const bf16x8*)&gS[n * XNP + q * 8];
    const bf16x8 a1 = *(const bf16x8*)&gS[n * XNP + 32 + q * 8];
    const unsigned short* wr = &wprojt[(size_t)(w * 16 + n) * 64];
    bf16x8 b0 = *(const bf16x8*)&wr[q * 8];
    bf16x8 b1_ = *(const bf16x8*)&wr[32 + q * 8];
    f32x4 acc = {0.f, 0.f, 0.f, 0.f};
    acc = __builtin_amdgcn_mfma_f32_16x16x32_bf16(a0, b0, acc, 0, 0, 0);
    acc = __builtin_amdgcn_mfma_f32_16x16x32_bf16(a1, b1_, acc, 0, 0, 0);
    float bias = bproj[w * 16 + n];
#pragma unroll
    for (int r = 0; r < 4; ++r)
      yS[(q * 4 + r) * 66 + w * 16 + n] = acc[r] + bias + lacc[r] + lbias;
  }
  __syncthreads();

  // Phase D: LN1 -> residual -> LN2 (16-lane group per token, 4 ch each)
  int tokL = t >> 4;
  int ch0 = (t & 15) * 4;
  size_t tok = bN + (size_t)(h0 + (tokL >> 3)) * Ww + w0 + (tokL & 7);
  float y[4];
#pragma unroll
  for (int i = 0; i < 4; ++i) y[i] = yS[tokL * 66 + ch0 + i];
  float s = y[0] + y[1] + y[2] + y[3];
  float s2 = y[0] * y[0] + y[1] * y[1] + y[2] * y[2] + y[3] * y[3];
#pragma unroll
  for (int off = 1; off <= 8; off <<= 1) {
    s += __shfl_xor(s, off, 64);
    s2 += __shfl_xor(s2, off, 64);
  }
  float m1 = s * (1.f / 64.f);
  float rs1 = rsqrtf(s2 * (1.f / 64.f) - m1 * m1 + EPS);
  float xv[4];
  *(float4*)xv = *(const float4*)&x[tok * 64 + ch0];
  float x2v[4];
  float t_s = 0.f, t_s2 = 0.f;
#pragma unroll
  for (int i = 0; i < 4; ++i) {
    float t1 = (y[i] - m1) * rs1 * g1[ch0 + i] + b1[ch0 + i];
    x2v[i] = xv[i] + t1;
    t_s += x2v[i];
    t_s2 += x2v[i] * x2v[i];
  }
#pragma unroll
  for (int off = 1; off <= 8; off <<= 1) {
    t_s += __shfl_xor(t_s, off, 64);
    t_s2 += __shfl_xor(t_s2, off, 64);
  }
  float m2 = t_s * (1.f / 64.f);
  float rs2 = rsqrtf(t_s2 * (1.f / 64.f) - m2 * m2 + EPS);
  *(float4*)&x2[tok * 64 + ch0] = *(float4*)x2v;
  unsigned int pk[2];
  {
    float a0_ = (x2v[0] - m2) * rs2 * g2[ch0] + b2[ch0];
    float a1_ = (x2v[1] - m2) * rs2 * g2[ch0 + 1] + b2[ch0 + 1];
    float a2_ = (x2v[2] - m2) * rs2 * g2[ch0 + 2] + b2[ch0 + 2];
    float a3_ = (x2v[3] - m2) * rs2 * g2[ch0 + 3] + b2[ch0 + 3];
    pk[0] = pack2(a0_, a1_);
    pk[1] = pack2(a2_, a3_);
  }
  *(uint2*)&xn2b[tok * 64 + ch0] = *(uint2*)pk;
}

// ---------------- K5: MSFN — depthwise in regs, 1x1 via MFMA ----------------
__global__ __launch_bounds__(256) void k_msfn(
    const unsigned short* __restrict__ xn2b, const float* __restrict__ x2,
    const float* __restrict__ w3t, const float* __restrict__ b3,
    const float* __restrict__ w5t, const float* __restrict__ b5,
    const unsigned short* __restrict__ w1bf, const float* __restrict__ b1,
    float* __restrict__ out) {
  __shared__ __align__(16) unsigned short xtS[6 * 12 * 64];
  __shared__ __align__(16) unsigned short tsS[16 * TSP];

  int bid = blockIdx.x;
  int b = bid / 196;
  int rem = bid % 196;
  int th = rem / 7, tw = rem % 7;
  int h0 = th * 2, w0 = tw * 8;
  size_t bN = (size_t)b * Nv;
  int t = threadIdx.x;

  unsigned int* xtU = (unsigned int*)xtS;
  for (int p = t; p < 6 * 12 * 32; p += 256) {
    int cp = p & 31, rc = p >> 5;
    int r = rc / 12, cc = rc % 12;
    int gh = h0 - 2 + r, gw = w0 - 2 + cc;
    unsigned int v = 0;
    if (gh >= 0 && gh < Hh && gw >= 0 && gw < Ww)
      v = *(const unsigned int*)&xn2b[(bN + gh * Ww + gw) * 64 + cp * 2];
    xtU[rc * 32 + cp] = v;
  }
  __syncthreads();

  int cin = t & 63, tg = t >> 6;
  int tr = tg >> 1, tc0 = (tg & 1) * 4;
  float win[5][8];
#pragma unroll
  for (int r = 0; r < 5; ++r)
#pragma unroll
    for (int c = 0; c < 8; ++c)
      win[r][c] = bf2f(xtS[((tr + r) * 12 + tc0 + c) * 64 + cin]);

  unsigned int* tsU = (unsigned int*)tsS;
#pragma unroll 1
  for (int m2 = 0; m2 < 4; m2 += 2) {
    float a3[2][9], a5[2][25], bb3[2], bb5[2];
#pragma unroll
    for (int mm = 0; mm < 2; ++mm) {
      int m = m2 + mm;
#pragma unroll
      for (int tap = 0; tap < 9; ++tap) a3[mm][tap] = w3t[(tap * 4 + m) * 64 + cin];
#pragma unroll
      for (int tap = 0; tap < 25; ++tap) a5[mm][tap] = w5t[(tap * 4 + m) * 64 + cin];
      bb3[mm] = b3[cin * 4 + m];
      bb5[mm] = b5[cin * 4 + m];
    }
#pragma unroll
    for (int tk = 0; tk < 4; ++tk) {
      int tok = tg * 4 + tk;
      unsigned int p3 = 0, p5 = 0;
#pragma unroll
      for (int mm = 0; mm < 2; ++mm) {
        float acc3 = bb3[mm];
#pragma unroll
        for (int kh = 0; kh < 3; ++kh)
#pragma unroll
          for (int kw2 = 0; kw2 < 3; ++kw2)
            acc3 += win[1 + kh][tk + 1 + kw2] * a3[mm][kh * 3 + kw2];
        float acc5 = bb5[mm];
#pragma unroll
        for (int kh = 0; kh < 5; ++kh)
#pragma unroll
          for (int kw2 = 0; kw2 < 5; ++kw2)
            acc5 += win[kh][tk + kw2] * a5[mm][kh * 5 + kw2];
        p3 |= (unsigned int)f2bf(acc3) << (16 * mm);
        p5 |= (unsigned int)f2bf(acc5) << (16 * mm);
      }
      tsU[(tok * TSP + cin * 4 + m2) >> 1] = p3;
      tsU[(tok * TSP + 256 + cin * 4 + m2) >> 1] = p5;
    }
  }
  __syncthreads();

  int wv = tg, lane = t & 63;
  int n16 = lane & 15, quad = lane >> 4;
  const unsigned short* wrow = &w1bf[(size_t)(wv * 16 + n16) * 512];
  f32x4 acc = {0.f, 0.f, 0.f, 0.f};
#pragma unroll 4
  for (int kk = 0; kk < 16; ++kk) {
    bf16x8 af = *(const bf16x8*)&tsS[n16 * TSP + kk * 32 + quad * 8];
    bf16x8 bfr = *(const bf16x8*)&wrow[kk * 32 + quad * 8];
    acc = __builtin_amdgcn_mfma_f32_16x16x32_bf16(af, bfr, acc, 0, 0, 0);
  }
  float bias = b1[wv * 16 + n16];
#pragma unroll
  for (int r = 0; r < 4; ++r) {
    int tok = quad * 4 + r;
    int trr = tok >> 3, tcc = tok & 7;
    size_t idx = (bN + (size_t)(h0 + trr) * Ww + w0 + tcc) * 64 + wv * 16 + n16;
    out[idx] = x2[idx] + acc[r] + bias;
  }
}

extern "C" void kernel_launch(void* const* d_in, const int* in_sizes, int n_in,
                              void* d_out, int out_size, void* d_ws, size_t ws_size,
                              hipStream_t stream) {
  const float* x = (const float*)d_in[0];
  const float* n1g = (const float*)d_in[1];
  const float* n1b = (const float*)d_in[2];
  const float* wq = (const float*)d_in[3];
  const float* bq = (const float*)d_in[4];
  const float* wkv = (const float*)d_in[5];
  const float* bkv = (const float*)d_in[6];
  const float* wproj = (const float*)d_in[7];
  const float* bproj = (const float*)d_in[8];
  const float* lw = (const float*)d_in[9];
  const float* lb = (const float*)d_in[10];
  const float* n2g = (const float*)d_in[11];
  const float* n2b = (const float*)d_in[12];
  const float* w3 = (const float*)d_in[13];
  const float* b3 = (const float*)d_in[14];
  const float* w5 = (const float*)d_in[15];
  const float* b5 = (const float*)d_in[16];
  const float* w1 = (const float*)d_in[17];
  const float* b1 = (const float*)d_in[18];
  float* out = (float*)d_out;

  float* ws = (float*)d_ws;
  const size_t TOK = (size_t)Bv * Nv * Cv;  // 802816
  float* vb = ws;
  float* sumv = vb + TOK;            // 256
  float* x2 = sumv + 256;
  float* w3t = x2 + TOK;             // 2304
  float* w5t = w3t + 2304;           // 6400
  float* qkvb = w5t + 6400;          // 192
  unsigned short* q16 = (unsigned short*)(qkvb + 192);
  unsigned short* k16 = q16 + TOK;
  unsigned short* xn2b = k16 + TOK;
  unsigned short* w1bf = xn2b + TOK;       // 64*512
  unsigned short* lwb = w1bf + 64 * 512;   // 64*576
  unsigned short* wqkvt = lwb + 64 * 576;  // 192*64
  unsigned short* wprojt = wqkvt + 192 * 64;  // 64*64
  unsigned int* top8ws = (unsigned int*)(wprojt + 64 * 64 + 64);  // 12544*64 uints

  k_transpose<<<144, 256, 0, stream>>>(w1, lw, w3, w5, wq, wkv, bq, bkv, wproj,
                                       w1bf, lwb, w3t, w5t, wqkvt, qkvb, wprojt, sumv);
  k_ln_qkv<<<Bv * 196, 256, 0, stream>>>(x, n1g, n1b, wqkvt, qkvb, q16, k16, vb, sumv);
  k_attn_topk<<<Bv * 196 * 4, 128, 0, stream>>>(q16, k16, top8ws);
  k_attn_proj<<<Bv * 196, 256, 0, stream>>>(top8ws, vb, sumv, x, lwb, lb, wprojt, bproj,
                                            n1g, n1b, n2g, n2b, x2, xn2b);
  k_msfn<<<Bv * 196, 256, 0, stream>>>(xn2b, x2, w3t, b3, w5t, b5, w1bf, b1, out);
}